// Round 11
// baseline (299.311 us; speedup 1.0000x reference)
//
#include <hip/hip_runtime.h>
#include <hip/hip_bf16.h>
#include <hip/hip_fp16.h>

#define OUT_F 4096
#define IN_F  4096
#define BATCH 4096
#define RANK  32
#define KPAD  4160   // 4096 + 32 (svd ext) + 32 (zero pad) = 65 * 64 = 130 * 32
#define NKB   130    // k32-blocks per row-panel
#define NT    65     // K tiles of 64

typedef __hip_bfloat16 bf16;
using bf16x8 = __attribute__((ext_vector_type(8))) short;
using f32x4  = __attribute__((ext_vector_type(4))) float;

// Fragment-major A layout: frag(rb=row>>4, kb=k>>5) = 1024B at ((rb*NKB+kb)*1024);
// within it, lane = koct*16 + (row&15) holds bf16x8 of k = kb*32 + koct*8 ..+8.

__device__ __forceinline__ void gload_lds16(const void* g, void* l) {
  __builtin_amdgcn_global_load_lds(
      (const __attribute__((address_space(1))) unsigned int*)g,
      (__attribute__((address_space(3))) unsigned int*)l,
      16, 0, 0);
}

__device__ __forceinline__ unsigned short bf16_bits(float f) {
  bf16 h = __float2bfloat16(f);
  return *(unsigned short*)&h;
}

#define SBAR() asm volatile("s_barrier" ::: "memory")

// ---------------------------------------------------------------------------
// Small prep: [0,512) VsT[r][c] = V[c][r]/s[c/128]; [512,1536) B ext cols:
// U values (0 for protected rows), 0 pad.
__global__ __launch_bounds__(256) void prep_misc(const float* __restrict__ v,
                                                 const float* __restrict__ scales,
                                                 const float* __restrict__ u,
                                                 const int* __restrict__ pidx,
                                                 bf16* __restrict__ vst,
                                                 bf16* __restrict__ B) {
  int bid = blockIdx.x;
  if (bid < 512) {
    int gid = bid * 256 + threadIdx.x;       // [0, 131072)
    int c = gid >> 5, r = gid & 31;
    float val = v[(size_t)c * RANK + r] / scales[c >> 7];
    vst[(size_t)r * IN_F + c] = __float2bfloat16(val);
  } else {
    int i = (bid - 512) * 256 + threadIdx.x; // [0, 262144)
    int o = i >> 6, j = i & 63;
    float val = (j < RANK) ? u[o * RANK + j] : 0.f;
#pragma unroll
    for (int jj = 0; jj < 32; ++jj)
      if (pidx[jj] == o) val = 0.f;          // protected rows: no SVD term
    B[(size_t)o * KPAD + IN_F + j] = __float2bfloat16(val);
  }
}

// ---------------------------------------------------------------------------
// Fused A-prep: phase 1 writes xs = x*s frag-major (coalesced reads via LDS
// transpose, XOR-swizzled); phase 2 computes T = xs @ VsT^T (K split over the
// 8 waves, LDS reduce) into frag kb=128, zeroes pad frag kb=129.
__global__ __launch_bounds__(512) void prep_a(const float* __restrict__ x,
                                              const float* __restrict__ scales,
                                              const bf16* __restrict__ vst,
                                              bf16* __restrict__ A) {
  __shared__ __align__(16) char lds[16384];
  int rb = blockIdx.x;                 // row-block 0..255
  int tid = threadIdx.x, w = tid >> 6, l = tid & 63;

  // ---- phase 1: 8 chunks of k512; wave w stages rows w*2, w*2+1 ----
  for (int c = 0; c < 8; ++c) {
#pragma unroll
    for (int j = 0; j < 2; ++j) {
      int r = w * 2 + j;               // 0..15
      const float* xr = x + (size_t)(rb * 16 + r) * IN_F + c * 512 + l * 8;
      float sv = scales[(c * 512 + l * 8) >> 7];
      float4 v0 = *(const float4*)xr;
      float4 v1 = *(const float4*)(xr + 4);
      bf16x8 pk;
      pk[0] = (short)bf16_bits(v0.x * sv); pk[1] = (short)bf16_bits(v0.y * sv);
      pk[2] = (short)bf16_bits(v0.z * sv); pk[3] = (short)bf16_bits(v0.w * sv);
      pk[4] = (short)bf16_bits(v1.x * sv); pk[5] = (short)bf16_bits(v1.y * sv);
      pk[6] = (short)bf16_bits(v1.z * sv); pk[7] = (short)bf16_bits(v1.w * sv);
      int kb = l >> 2;                 // local frag 0..15 (koct = l&3)
      int byte = kb * 1024 + (((l & 3) << 4) + r) * 16;
      *(bf16x8*)(lds + (byte ^ ((kb & 7) << 4))) = pk;
    }
    __syncthreads();
#pragma unroll
    for (int j = 0; j < 2; ++j) {
      int f = w * 2 + j;
      int byte = f * 1024 + l * 16;
      bf16x8 pk = *(const bf16x8*)(lds + (byte ^ ((f & 7) << 4)));
      *(bf16x8*)(A + ((size_t)rb * NKB + c * 16 + f) * 512 + (size_t)l * 8) = pk;
    }
    __syncthreads();
  }

  // ---- phase 2: T for these 16 rows; wave w covers k32 [w*16, w*16+16) ----
  const bf16* abase = A + (size_t)rb * NKB * 512 + (size_t)l * 8;
  const bf16* brow0 = vst + (size_t)(l & 15) * IN_F + ((l >> 4) << 3);
  const bf16* brow1 = vst + (size_t)(16 + (l & 15)) * IN_F + ((l >> 4) << 3);
  f32x4 acc0 = (f32x4){0.f, 0.f, 0.f, 0.f};
  f32x4 acc1 = (f32x4){0.f, 0.f, 0.f, 0.f};
#pragma unroll 8
  for (int k32 = w * 16; k32 < w * 16 + 16; ++k32) {
    bf16x8 av  = *(const bf16x8*)(abase + (size_t)k32 * 512);
    bf16x8 bv0 = *(const bf16x8*)(brow0 + k32 * 32);
    bf16x8 bv1 = *(const bf16x8*)(brow1 + k32 * 32);
    acc0 = __builtin_amdgcn_mfma_f32_16x16x32_bf16(av, bv0, acc0, 0, 0, 0);
    acc1 = __builtin_amdgcn_mfma_f32_16x16x32_bf16(av, bv1, acc1, 0, 0, 0);
  }
  *(f32x4*)(lds + w * 2048 + l * 32)      = acc0;
  *(f32x4*)(lds + w * 2048 + l * 32 + 16) = acc1;
  __syncthreads();
  if (w == 1) {  // zero pad frag kb=129
    bf16x8 z = (bf16x8){0, 0, 0, 0, 0, 0, 0, 0};
    *(bf16x8*)(A + ((size_t)rb * NKB + 129) * 512 + (size_t)l * 8) = z;
  }
  if (w == 0) {
#pragma unroll
    for (int ww = 1; ww < 8; ++ww) {
      acc0 += *(const f32x4*)(lds + ww * 2048 + l * 32);
      acc1 += *(const f32x4*)(lds + ww * 2048 + l * 32 + 16);
    }
    bf16* base = A + ((size_t)rb * NKB + 128) * 512;
    int c0 = l & 15, c1 = 16 + (l & 15);
#pragma unroll
    for (int r = 0; r < 4; ++r) {
      int row15 = ((l >> 4) << 2) + r;
      base[(c0 >> 3) * 128 + row15 * 8 + (c0 & 7)] = __float2bfloat16(acc0[r]);
      base[(c1 >> 3) * 128 + row15 * 8 + (c1 & 7)] = __float2bfloat16(acc1[r]);
    }
  }
}

// ---------------------------------------------------------------------------
// B-unpack with fused protected-row overwrite. lo nibbles -> rows 0..2047,
// hi nibbles -> rows 2048..4095; protected rows get pc/s instead.
__global__ __launch_bounds__(256) void prep_b(const int* __restrict__ packed,
                                              const float* __restrict__ pc,
                                              const float* __restrict__ scales,
                                              const int* __restrict__ pidx,
                                              bf16* __restrict__ B) {
  size_t i = (size_t)blockIdx.x * 256 + threadIdx.x;   // [0, 2097152)
  int4 p = ((const int4*)packed)[i];
  size_t e = i * 4;
  int o = (int)(e >> 12);
  int c = (int)(e & 4095);
  int pi_lo = -1, pi_hi = -1;
#pragma unroll
  for (int j = 0; j < 32; ++j) {
    int pr = pidx[j];
    if (pr == o) pi_lo = j;
    if (pr == o + 2048) pi_hi = j;
  }
  int vals[4] = {p.x, p.y, p.z, p.w};
  unsigned short lo[4], hi[4];
#pragma unroll
  for (int j = 0; j < 4; ++j) {
    lo[j] = bf16_bits((float)((vals[j] & 15) - 8));
    hi[j] = bf16_bits((float)(((vals[j] >> 4) & 15) - 8));
  }
  if (pi_lo >= 0) {
    float sv = scales[c >> 7];
#pragma unroll
    for (int j = 0; j < 4; ++j)
      lo[j] = bf16_bits(pc[(size_t)pi_lo * IN_F + c + j] / sv);
  }
  if (pi_hi >= 0) {
    float sv = scales[c >> 7];
#pragma unroll
    for (int j = 0; j < 4; ++j)
      hi[j] = bf16_bits(pc[(size_t)pi_hi * IN_F + c + j] / sv);
  }
  *(ushort4*)(B + (size_t)o * KPAD + c) = make_ushort4(lo[0], lo[1], lo[2], lo[3]);
  *(ushort4*)(B + (size_t)(o + 2048) * KPAD + c) = make_ushort4(hi[0], hi[1], hi[2], hi[3]);
}

// ---------------------------------------------------------------------------
// Main GEMM, 256x128 tile, BK=64, 8 waves (4 row-bands x 2 col-bands of 64),
// TWO blocks per CU (LDS 64KB, <=128 regs) so one block's barrier/latency
// stalls are covered by the other block's compute.
// A: frag-major global -> VGPR (coalesced 1KB/frag); A(t+1) issued between
//    the end-of-tile vmcnt and the barrier (global-only: legal across SBAR).
// B: 4-deep LDS pipeline (4 x 16KB) via global_load_lds, XOR-swizzled reads;
//    2 staging rounds/tile at phases 1,3; end-of-tile vmcnt(2) (never 0).
__global__ __launch_bounds__(512, 4) void gemm_bt(const bf16* __restrict__ A,
                                                  const bf16* __restrict__ B,
                                                  float* __restrict__ out) {
  __shared__ __align__(16) bf16 Bs[4 * 128 * 64];   // 64 KiB

  int bid = blockIdx.x;
  // XCD swizzle: 512 blocks, 8 XCDs, 64 contiguous per XCD.
  int swz = (bid & 7) * 64 + (bid >> 3);
  int brow = (swz >> 5) << 8;   // 16 M-tiles of 256 rows
  int bcol = (swz & 31) << 7;   // 32 N-tiles of 128 cols

  int tid = threadIdx.x;
  int lane = tid & 63;
  int wave = tid >> 6;
  int wr = wave >> 1;           // 0..3 : 64-row band
  int wc = wave & 1;            // 0..1 : 64-col band

  f32x4 acc[4][4];
#pragma unroll
  for (int m = 0; m < 4; ++m)
#pragma unroll
    for (int n = 0; n < 4; ++n)
      acc[m][n] = (f32x4){0.f, 0.f, 0.f, 0.f};

  // A frag 32-bit offsets (A < 34MB): frag (m,kk,t) at aoff[m] + (2t+kk)*1024.
  unsigned aoff[4];
  int rbw = (brow >> 4) + wr * 4;
#pragma unroll
  for (int m = 0; m < 4; ++m)
    aoff[m] = (unsigned)((rbw + m) * NKB) * 1024u + (unsigned)lane * 16u;
  const char* Ab = (const char*)A;

  // B LDS frag byte offsets within one 16KB buffer (kk=0; kk=1 is ^64).
  int boff[4];
#pragma unroll
  for (int n = 0; n < 4; ++n) {
    int rbr = wc * 64 + n * 16 + (lane & 15);
    int s0 = (lane >> 4) ^ (rbr & 7);
    boff[n] = rbr * 128 + (s0 << 4);
  }

  // B staging: 2 rounds/tile; round q: idx = q*512+tid -> row=idx>>3, slot=idx&7.
  const bf16* gB[2]; int lB[2];
#pragma unroll
  for (int q = 0; q < 2; ++q) {
    int idx = q * 512 + tid;
    int row = idx >> 3, slot = idx & 7;
    gB[q] = B + (size_t)(bcol + row) * KPAD + ((slot ^ (row & 7)) << 3);
    lB[q] = idx << 4;          // byte offset within a buffer
  }
  char* bs0 = (char*)Bs;

  // ---- prologue: A(0); stage B(0),B(1),B(2); vmcnt(4) keeps B(1),B(2) flying.
  bf16x8 a[4][2];
#pragma unroll
  for (int m = 0; m < 4; ++m)
#pragma unroll
    for (int kk = 0; kk < 2; ++kk)
      a[m][kk] = *(const bf16x8*)(Ab + aoff[m] + kk * 1024);
#pragma unroll
  for (int kt = 0; kt < 3; ++kt)
#pragma unroll
    for (int q = 0; q < 2; ++q)
      gload_lds16(gB[q] + kt * 64, bs0 + kt * 16384 + lB[q]);
  asm volatile("s_waitcnt vmcnt(4)" ::: "memory");
  SBAR();

  // ---- K loop: 4 phases (by n), stages at p1/p3, one vmcnt(2)+SBAR per tile.
  for (int t = 0; t < NT; ++t) {
    const char* rb_ = bs0 + (t & 3) * 16384;         // read buffer
    char* wb = bs0 + ((t + 3) & 3) * 16384;          // stage dest buffer
    int kt = (t + 3 < NT) ? (t + 3) : (NT - 1);      // clamped (uniform count)
#pragma unroll
    for (int p = 0; p < 4; ++p) {
      bf16x8 bv0 = *(const bf16x8*)(rb_ + boff[p]);
      bf16x8 bv1 = *(const bf16x8*)(rb_ + (boff[p] ^ 64));
      if (p == 1) gload_lds16(gB[0] + (size_t)kt * 64, wb + lB[0]);
      if (p == 3) gload_lds16(gB[1] + (size_t)kt * 64, wb + lB[1]);
      __builtin_amdgcn_s_setprio(1);
#pragma unroll
      for (int m = 0; m < 4; ++m) {
        acc[m][p] = __builtin_amdgcn_mfma_f32_16x16x32_bf16(a[m][0], bv0, acc[m][p], 0, 0, 0);
        acc[m][p] = __builtin_amdgcn_mfma_f32_16x16x32_bf16(a[m][1], bv1, acc[m][p], 0, 0, 0);
      }
      __builtin_amdgcn_s_setprio(0);
    }
    asm volatile("s_waitcnt vmcnt(2)" ::: "memory");
    if (t + 1 < NT) {            // A(t+1): global-only, legal across barrier
      unsigned ko = (unsigned)(2 * (t + 1)) * 1024u;
#pragma unroll
      for (int m = 0; m < 4; ++m)
#pragma unroll
        for (int kk = 0; kk < 2; ++kk)
          a[m][kk] = *(const bf16x8*)(Ab + aoff[m] + ko + kk * 1024);
    }
    SBAR();
  }

  // ---- epilogue: C/D col=lane&15 (o), row=(lane>>4)*4+r (batch); fp16 round.
#pragma unroll
  for (int m = 0; m < 4; ++m)
#pragma unroll
    for (int n = 0; n < 4; ++n)
#pragma unroll
      for (int r = 0; r < 4; ++r) {
        int mm = brow + wr * 64 + m * 16 + ((lane >> 4) << 2) + r;
        int nn = bcol + wc * 64 + n * 16 + (lane & 15);
        out[(size_t)mm * OUT_F + nn] = __half2float(__float2half(acc[m][n][r]));
      }
  asm volatile("s_waitcnt vmcnt(0)" ::: "memory");  // drain tail DMAs
}

// ---------------------------------------------------------------------------
extern "C" void kernel_launch(void* const* d_in, const int* in_sizes, int n_in,
                              void* d_out, int out_size, void* d_ws, size_t ws_size,
                              hipStream_t stream) {
  const float* x      = (const float*)d_in[0];
  const int*   packed = (const int*)d_in[1];
  const float* scales = (const float*)d_in[2];
  const float* svd_u  = (const float*)d_in[3];
  const float* svd_v  = (const float*)d_in[4];
  const float* pc     = (const float*)d_in[5];
  const int*   pidx   = (const int*)d_in[6];
  float* out = (float*)d_out;

  bf16* A   = (bf16*)d_ws;                     // frag-major, 34.1 MB
  bf16* B   = A + (size_t)BATCH * KPAD;        // [OUT_F][KPAD] = 34.1 MB
  bf16* vst = B + (size_t)OUT_F * KPAD;        // [RANK][IN_F]  = 0.25 MB

  prep_misc<<<1536, 256, 0, stream>>>(svd_v, scales, svd_u, pidx, vst, B);
  prep_a   <<<256,  512, 0, stream>>>(x, scales, vst, A);
  prep_b   <<<8192, 256, 0, stream>>>(packed, pc, scales, pidx, B);
  gemm_bt  <<<512,  512, 0, stream>>>(A, B, out);
}